// Round 22
// baseline (487.700 us; speedup 1.0000x reference)
//
#include <hip/hip_runtime.h>
#include <hip/hip_fp16.h>

// Residual VQ on MI355X (gfx950) — MFMA distance engine, barrier-free,
// packed-key tracker + wave-cooperative exact rescue.
// z: [8, 32768, 32] f32; codebooks: [10, 512, 32] f32.
// Outputs (flat f32 in d_out): quantized [B,N,D], indices [B,N,Q] (as float),
// commit_loss [Q] (zeros).
//
// R22 = R21 (uniform-K, union LDS, batch-2 merged tracker — absmax 0.0,
// 469 us) with the merge widened to BATCH-4 (quad): two-smallest-of-4 via
//   a=min(kA,kB); b=max(kA,kB); c=min(kC,kD); d=max(kC,kD);
//   kmin=min(a,c); ksec=min3(max(a,c),b,d);
// folded into (m1,m2):
//   pmx=max(m1_old,kmin); m2=min3(m2,ksec,pmx); m1=min(m1,kmin);
// (case-proved; distinct ascending ids keep first-min tie-break).
// 14 VALU/quad/slot vs 16, and 8 fragment loads + 48 MFMAs in flight per
// quad. Pure C (min3 folds to VOP3; no inline asm — R17 lesson).
// All exact math (numpy tree, ST chain), split bit-pattern, window,
// prep/replay bit-identical to proven R21.

#define RVQ_Q 10
#define RVQ_C 512
#define RVQ_D 32

static constexpr int  NPTS      = 262144;
static constexpr long IDX_OFF   = (long)NPTS * RVQ_D;
static constexpr long LOSS_OFF  = IDX_OFF + (long)NPTS * RVQ_Q;
static constexpr int  BPTS      = 64;            // points per block (1 wave)
static constexpr int  SCB_U4    = RVQ_Q * 32 * 8 * 16;   // 40960 uint4
static constexpr long NORM_OFF  = (long)SCB_U4 * 4;      // floats into scratch
static constexpr unsigned KMASK = 0xFFFFFE00u;   // drop 9 bits for cnd

typedef __attribute__((ext_vector_type(32))) float f32x32;
typedef __attribute__((ext_vector_type(8)))  short short8;
typedef __attribute__((ext_vector_type(4)))  float f32x4;

// ---------------------------------------------------------------------------
// reference-exact numpy reduction tree (proven absmax 0.0 in R1/R3-R21)
__device__ __forceinline__ float tree_dot(const f32x32& x, const f32x32& y) {
    float a[8];
#pragma unroll
    for (int j = 0; j < 8; ++j) a[j] = x[j] * y[j];
#pragma unroll
    for (int j = 8; j < RVQ_D; ++j) a[j & 7] = fmaf(x[j], y[j], a[j & 7]);
    return ((a[0] + a[1]) + (a[2] + a[3])) + ((a[4] + a[5]) + (a[6] + a[7]));
}

__device__ __forceinline__ f32x32 st_update(const f32x32& r, const f32x32& gv) {
    const f32x32 tt  = gv - r;
    const f32x32 qst = r + tt;
    return r - qst;
}

__device__ __forceinline__ short8 as_s8(uint4 u) {
    union { uint4 a; short8 b; } x; x.a = u; return x.b;
}
__device__ __forceinline__ unsigned pk_hi(float v0, float v1) {
    return (__float_as_uint(v0) >> 16) | (__float_as_uint(v1) & 0xFFFF0000u);
}
__device__ __forceinline__ float lo_rem(float v) {
    return v - __uint_as_float(__float_as_uint(v) & 0xFFFF0000u);
}
__device__ __forceinline__ unsigned umn(unsigned a, unsigned b) { return a < b ? a : b; }
__device__ __forceinline__ unsigned umx(unsigned a, unsigned b) { return a > b ? a : b; }
__device__ __forceinline__ unsigned umn3(unsigned a, unsigned b, unsigned c) {
    return umn(umn(a, b), c);   // folds to v_min3_u32
}

// ---------------------------------------------------------------------------
// Kernel P: codebook -> bf16 hi/lo MFMA fragments + exact norms (R14-proven).
__global__ __launch_bounds__(64) void rvq_prep(const float* __restrict__ cb,
                                               uint4* __restrict__ scb,
                                               float* __restrict__ normg) {
    const int cnd = blockIdx.x * 64 + threadIdx.x;       // 0..5119
    const f32x32 c = *(const f32x32*)(cb + (long)cnd * RVQ_D);
    normg[cnd] = tree_dot(c, c);
    const int q = cnd >> 9, cq = cnd & 511, ct = cq >> 4, col = cq & 15;
    const long base = (long)(q * 32 + ct) * 128 + col;
#pragma unroll
    for (int g = 0; g < 4; ++g)
#pragma unroll
        for (int sp = 0; sp < 2; ++sp) {
            unsigned u[4];
#pragma unroll
            for (int pr = 0; pr < 4; ++pr) {
                const int j = g * 8 + pr * 2;
                float v0 = c[j], v1 = c[j + 1];
                if (sp == 1) { v0 = lo_rem(v0); v1 = lo_rem(v1); }
                u[pr] = pk_hi(v0, v1);
            }
            scb[base + (g * 2 + sp) * 16] = make_uint4(u[0], u[1], u[2], u[3]);
        }
}

// ---------------------------------------------------------------------------
// Kernel S: search. ONE wave per block, 64 points, no __syncthreads.
// LDS union: ptfrag (E->hoist) shares 8 KB with m1key/m2h (publish->R).
__global__ __launch_bounds__(64, 2) void rvq_search(const float* __restrict__ z,
                                                    const float* __restrict__ cb,
                                                    const uint4* __restrict__ scb,
                                                    const float* __restrict__ normg,
                                                    float* __restrict__ iout) {
    __shared__ __align__(16) unsigned char smem[BPTS * 8 * 16];   // 8 KB union
    __shared__ float snorm_l[RVQ_C];              // 2 KB EXACT norms (no K!)
    __shared__ float rrbuf[BPTS];                 // 256 B

    uint4*          ptfrag  = (uint4*)smem;                          // 8 KB
    unsigned*       m1key_s = (unsigned*)smem;                       // 4.25 KB
    unsigned short* m2h_s   = (unsigned short*)(smem + BPTS * 17 * 4); // 2.1 KB

    const int t    = threadIdx.x;          // 0..63 == lane
    const int col  = t & 15;
    const int g    = t >> 4;
    const int sw0  = g ^ (col & 7);
    const int sw1  = (4 + g) ^ (col & 7);
    const long p   = (long)blockIdx.x * BPTS + t;

    f32x32 r = *(const f32x32*)(z + p * RVQ_D);

#pragma unroll 1
    for (int q = 0; q < RVQ_Q; ++q) {
        const float* cbq  = cb + (long)q * RVQ_C * RVQ_D;
        const uint4* scbq = scb + (long)q * 4096;

        // ---- norms -> LDS + ccm (wave max), rr + rrmax (wave max)
        float ccm = 0.0f;
#pragma unroll
        for (int n = 0; n < 8; ++n) {
            const float v = normg[q * RVQ_C + t + 64 * n];
            snorm_l[t + 64 * n] = v;
            ccm = fmaxf(ccm, v);
        }
#pragma unroll
        for (int m_ = 1; m_ <= 32; m_ <<= 1) ccm = fmaxf(ccm, __shfl_xor(ccm, m_, 64));

        const float rr = tree_dot(r, r);
        rrbuf[t] = rr;
        float rrmax = rr;
#pragma unroll
        for (int m_ = 1; m_ <= 32; m_ <<= 1) rrmax = fmaxf(rrmax, __shfl_xor(rrmax, m_, 64));
        const float biasW = (rrmax + ccm) * 0.001953125f;   // 2^-9 window
        const float K     = rrmax + biasW;   // uniform shift (R16/R17/R20-proven)

        // ---- E phase: -2r bf16 split -> ptfrag (proven bit-pattern)
        {
            const f32x32 s = -2.0f * r;
#pragma unroll
            for (int sp = 0; sp < 2; ++sp)
#pragma unroll
                for (int gg = 0; gg < 4; ++gg) {
                    unsigned u[4];
#pragma unroll
                    for (int pr = 0; pr < 4; ++pr) {
                        const int j = gg * 8 + pr * 2;
                        float v0 = s[j], v1 = s[j + 1];
                        if (sp == 1) { v0 = lo_rem(v0); v1 = lo_rem(v1); }
                        u[pr] = pk_hi(v0, v1);
                    }
                    ptfrag[t * 8 + ((sp * 4 + gg) ^ (t & 7))] =
                        make_uint4(u[0], u[1], u[2], u[3]);
                }
        }

        // ---- hoist A fragments (registers for whole sweep)
        uint4 ahr[4], alr[4];
#pragma unroll
        for (int TL = 0; TL < 4; ++TL) {
            ahr[TL] = ptfrag[(TL * 16 + col) * 8 + sw0];
            alr[TL] = ptfrag[(TL * 16 + col) * 8 + sw1];
        }

        // ---- packed-key trackers (registers, pure C ops)
        unsigned m1k[4][4], m2k[4][4];
#pragma unroll
        for (int a = 0; a < 4; ++a)
#pragma unroll
            for (int b = 0; b < 4; ++b) { m1k[a][b] = 0xFFFFFFFFu; m2k[a][b] = 0xFFFFFFFFu; }

        int cndv = col;   // candidate id of this lane's column

        // ---- sweep: candidate tile QUADS, batch-4 merged tracker
#pragma unroll 1
        for (int ct = 0; ct < 32; ct += 4) {
            const short8 bhA = as_s8(scbq[ct * 128 + g * 32 + col]);
            const short8 blA = as_s8(scbq[ct * 128 + g * 32 + col + 16]);
            const short8 bhB = as_s8(scbq[(ct + 1) * 128 + g * 32 + col]);
            const short8 blB = as_s8(scbq[(ct + 1) * 128 + g * 32 + col + 16]);
            const short8 bhC = as_s8(scbq[(ct + 2) * 128 + g * 32 + col]);
            const short8 blC = as_s8(scbq[(ct + 2) * 128 + g * 32 + col + 16]);
            const short8 bhD = as_s8(scbq[(ct + 3) * 128 + g * 32 + col]);
            const short8 blD = as_s8(scbq[(ct + 3) * 128 + g * 32 + col + 16]);
            const float cKA = snorm_l[ct * 16 + col] + K;
            const float cKB = snorm_l[(ct + 1) * 16 + col] + K;
            const float cKC = snorm_l[(ct + 2) * 16 + col] + K;
            const float cKD = snorm_l[(ct + 3) * 16 + col] + K;
            const f32x4 accinA = {cKA, cKA, cKA, cKA};
            const f32x4 accinB = {cKB, cKB, cKB, cKB};
            const f32x4 accinC = {cKC, cKC, cKC, cKC};
            const f32x4 accinD = {cKD, cKD, cKD, cKD};
#pragma unroll
            for (int TL = 0; TL < 4; ++TL) {
                const short8 ah = as_s8(ahr[TL]);
                const short8 al = as_s8(alr[TL]);
                f32x4 accA = __builtin_amdgcn_mfma_f32_16x16x32_bf16(ah, bhA, accinA, 0, 0, 0);
                accA = __builtin_amdgcn_mfma_f32_16x16x32_bf16(al, bhA, accA, 0, 0, 0);
                accA = __builtin_amdgcn_mfma_f32_16x16x32_bf16(ah, blA, accA, 0, 0, 0);
                f32x4 accB = __builtin_amdgcn_mfma_f32_16x16x32_bf16(ah, bhB, accinB, 0, 0, 0);
                accB = __builtin_amdgcn_mfma_f32_16x16x32_bf16(al, bhB, accB, 0, 0, 0);
                accB = __builtin_amdgcn_mfma_f32_16x16x32_bf16(ah, blB, accB, 0, 0, 0);
                f32x4 accC = __builtin_amdgcn_mfma_f32_16x16x32_bf16(ah, bhC, accinC, 0, 0, 0);
                accC = __builtin_amdgcn_mfma_f32_16x16x32_bf16(al, bhC, accC, 0, 0, 0);
                accC = __builtin_amdgcn_mfma_f32_16x16x32_bf16(ah, blC, accC, 0, 0, 0);
                f32x4 accD = __builtin_amdgcn_mfma_f32_16x16x32_bf16(ah, bhD, accinD, 0, 0, 0);
                accD = __builtin_amdgcn_mfma_f32_16x16x32_bf16(al, bhD, accD, 0, 0, 0);
                accD = __builtin_amdgcn_mfma_f32_16x16x32_bf16(ah, blD, accD, 0, 0, 0);
#pragma unroll
                for (int i = 0; i < 4; ++i) {
                    const unsigned kA = (__float_as_uint(accA[i]) & KMASK) | (unsigned)cndv;
                    const unsigned kB = (__float_as_uint(accB[i]) & KMASK) | (unsigned)(cndv + 16);
                    const unsigned kC = (__float_as_uint(accC[i]) & KMASK) | (unsigned)(cndv + 32);
                    const unsigned kD = (__float_as_uint(accD[i]) & KMASK) | (unsigned)(cndv + 48);
                    // two smallest of {kA..kD}:
                    const unsigned a_ = umn(kA, kB), b_ = umx(kA, kB);
                    const unsigned c_ = umn(kC, kD), d_ = umx(kC, kD);
                    const unsigned kmin = umn(a_, c_);
                    const unsigned ksec = umn3(umx(a_, c_), b_, d_);
                    // fold into (m1,m2):
                    const unsigned pmx = umx(m1k[TL][i], kmin);
                    m2k[TL][i] = umn3(m2k[TL][i], ksec, pmx);
                    m1k[TL][i] = umn(m1k[TL][i], kmin);
                }
            }
            cndv += 64;
        }

        // ---- publish trackers (ptfrag dead; union reuse safe in wave order)
#pragma unroll
        for (int TL = 0; TL < 4; ++TL)
#pragma unroll
            for (int i = 0; i < 4; ++i) {
                const int pt = TL * 16 + 4 * g + i;
                m1key_s[pt * 17 + col] = m1k[TL][i];
                const float m2f = __uint_as_float(m2k[TL][i] & KMASK);
                m2h_s[pt * 17 + col] = __half_as_ushort(__float2half_rd(m2f));
            }

        // ---- R phase (R20-proven): admitted-id evals + coop scans
        float bd = __builtin_inff(); int bi = 0;
        unsigned smask = 0;
        {
            unsigned mmk = 0xFFFFFFFFu;
#pragma unroll
            for (int c = 0; c < 16; ++c) mmk = umn(mmk, m1key_s[t * 17 + c]);
            const float thrf = __uint_as_float(mmk & KMASK) + (rr + ccm) * 0.001953125f;

            auto evalExact = [&](int cnd) {
                const f32x32 cvv = *(const f32x32*)(cbq + (long)cnd * RVQ_D);
                const float d = fmaf(-2.0f, tree_dot(r, cvv), rr) + snorm_l[cnd];
                if (d < bd || (d == bd && cnd < bi)) { bd = d; bi = cnd; }
            };
#pragma unroll 1
            for (int c = 0; c < 16; ++c) {
                const unsigned k1 = m1key_s[t * 17 + c];
                const bool adm = __uint_as_float(k1 & KMASK) <= thrf;
                const bool scn = __half2float(__ushort_as_half(m2h_s[t * 17 + c])) <= thrf;
                smask |= (scn ? 1u : 0u) << c;
                if (adm && !scn) evalExact((int)(k1 & 511u));
            }

            // cooperative full-class scans (rare; R15-proven)
            unsigned long long bal = __ballot(smask != 0);
            const int l31 = t & 31;
            while (bal) {
                const int b = (int)__builtin_ctzll(bal); bal &= bal - 1;
                unsigned sm = (unsigned)__shfl((int)smask, b, 64);
                f32x32 rb;
#pragma unroll
                for (int j = 0; j < RVQ_D; ++j) rb[j] = __shfl(r[j], b, 64);
                const float rrb = __shfl(rr, b, 64);
                while (sm) {
                    const int c = (int)__builtin_ctz(sm); sm &= sm - 1;
                    int  ci = l31 * 16 + c;
                    const f32x32 cvv = *(const f32x32*)(cbq + (long)ci * RVQ_D);
                    float d = fmaf(-2.0f, tree_dot(rb, cvv), rrb) + snorm_l[ci];
#pragma unroll
                    for (int m_ = 1; m_ <= 32; m_ <<= 1) {
                        const float od = __shfl_xor(d, m_, 64);
                        const int   oi = __shfl_xor(ci, m_, 64);
                        if (od < d || (od == d && oi < ci)) { d = od; ci = oi; }
                    }
                    if (t == b) {
                        if (d < bd || (d == bd && ci < bi)) { bd = d; bi = ci; }
                    }
                }
            }
        }

        iout[p * RVQ_Q + q] = (float)bi;
        const f32x32 gw = *(const f32x32*)(cbq + (long)bi * RVQ_D);
        r = st_update(r, gw);
    }
}

// ---------------------------------------------------------------------------
// Replay: bit-exact straight-through chain from stored indices (proven
// pre+post-timing R3-R21). Overwrites the scratch region with quantized.
__global__ __launch_bounds__(256) void rvq_replay(const float* __restrict__ z,
                                                  const float* __restrict__ cb,
                                                  float* __restrict__ out) {
    const int p = blockIdx.x * 256 + threadIdx.x;

    float r[RVQ_D], oacc[RVQ_D];
    {
        const float4* zp = (const float4*)(z + (long)p * RVQ_D);
#pragma unroll
        for (int w = 0; w < 8; ++w) {
            const float4 v = zp[w];
            r[w * 4 + 0] = v.x; r[w * 4 + 1] = v.y;
            r[w * 4 + 2] = v.z; r[w * 4 + 3] = v.w;
        }
    }
#pragma unroll
    for (int d = 0; d < RVQ_D; ++d) oacc[d] = 0.0f;

#pragma unroll 1
    for (int q = 0; q < RVQ_Q; ++q) {
        const int idx = (int)out[IDX_OFF + (long)p * RVQ_Q + q];
        const float4* cwb = (const float4*)(cb + ((long)q * RVQ_C + idx) * RVQ_D);
        float cwv[RVQ_D];
#pragma unroll
        for (int w = 0; w < 8; ++w) {
            const float4 v = cwb[w];
            cwv[w * 4 + 0] = v.x; cwv[w * 4 + 1] = v.y;
            cwv[w * 4 + 2] = v.z; cwv[w * 4 + 3] = v.w;
        }
#pragma unroll
        for (int d = 0; d < RVQ_D; ++d) {
            const float qst = r[d] + (cwv[d] - r[d]);
            oacc[d] += qst;
            r[d] = r[d] - qst;
        }
    }

    float4* qo = (float4*)(out + (long)p * RVQ_D);
#pragma unroll
    for (int w = 0; w < 8; ++w) {
        float4 v;
        v.x = oacc[w * 4 + 0]; v.y = oacc[w * 4 + 1];
        v.z = oacc[w * 4 + 2]; v.w = oacc[w * 4 + 3];
        qo[w] = v;
    }

    if (p < RVQ_Q) out[LOSS_OFF + p] = 0.0f;
}

// ---------------------------------------------------------------------------
extern "C" void kernel_launch(void* const* d_in, const int* in_sizes, int n_in,
                              void* d_out, int out_size, void* d_ws, size_t ws_size,
                              hipStream_t stream) {
    const float* z  = (const float*)d_in[0];
    const float* cb = (const float*)d_in[1];
    float* out = (float*)d_out;
    (void)d_ws; (void)ws_size;   // no workspace (R6 lesson)

    // scratch inside the quantized region (rewritten every call; replay
    // overwrites it at the end — R4/R5/R14-R21-proven pattern)
    uint4* scb   = (uint4*)out;                 // 655 KB fragments
    float* normg = out + NORM_OFF;              // 5120 exact norms
    float* iout  = out + IDX_OFF;

    rvq_prep  <<<(RVQ_Q * RVQ_C) / 64, 64, 0, stream>>>(cb, scb, normg);
    rvq_search<<<NPTS / BPTS, BPTS, 0, stream>>>(z, cb, scb, normg, iout);
    rvq_replay<<<NPTS / 256, 256, 0, stream>>>(z, cb, out);
}

// Round 23
// 467.860 us; speedup vs baseline: 1.0424x; 1.0424x over previous
//
#include <hip/hip_runtime.h>
#include <hip/hip_fp16.h>

// Residual VQ on MI355X (gfx950) — MFMA distance engine, barrier-free,
// packed-key tracker + wave-cooperative exact rescue.
// z: [8, 32768, 32] f32; codebooks: [10, 512, 32] f32.
// Outputs (flat f32 in d_out): quantized [B,N,D], indices [B,N,Q] (as float),
// commit_loss [Q] (zeros).
//
// R23 = R21 VERBATIM (best: 469 us, absmax 0.0). R22's batch-4 merge
// regressed (488 us: longer serial merge chain + lost unroll-2 ILP), which
// triggered the pre-committed convergence criterion. This restores the
// proven best configuration: uniform-K C-init, union LDS, BATCH-2 merged
// tracker (p=min(kA,kB); med=max(p,min(max(kA,kB),m1)); m2=min(m2,med);
// m1=min(m1,p)), LDS publish, owner R-phase with E[~1.05] exact evals,
// wave-cooperative class scans, prep/replay kernels.
// Session: 2738 -> 469 us (5.8x), bit-exact at every passing round.

#define RVQ_Q 10
#define RVQ_C 512
#define RVQ_D 32

static constexpr int  NPTS      = 262144;
static constexpr long IDX_OFF   = (long)NPTS * RVQ_D;
static constexpr long LOSS_OFF  = IDX_OFF + (long)NPTS * RVQ_Q;
static constexpr int  BPTS      = 64;            // points per block (1 wave)
static constexpr int  SCB_U4    = RVQ_Q * 32 * 8 * 16;   // 40960 uint4
static constexpr long NORM_OFF  = (long)SCB_U4 * 4;      // floats into scratch
static constexpr unsigned KMASK = 0xFFFFFE00u;   // drop 9 bits for cnd

typedef __attribute__((ext_vector_type(32))) float f32x32;
typedef __attribute__((ext_vector_type(8)))  short short8;
typedef __attribute__((ext_vector_type(4)))  float f32x4;

// ---------------------------------------------------------------------------
// reference-exact numpy reduction tree (proven absmax 0.0 in R1/R3-R22)
__device__ __forceinline__ float tree_dot(const f32x32& x, const f32x32& y) {
    float a[8];
#pragma unroll
    for (int j = 0; j < 8; ++j) a[j] = x[j] * y[j];
#pragma unroll
    for (int j = 8; j < RVQ_D; ++j) a[j & 7] = fmaf(x[j], y[j], a[j & 7]);
    return ((a[0] + a[1]) + (a[2] + a[3])) + ((a[4] + a[5]) + (a[6] + a[7]));
}

__device__ __forceinline__ f32x32 st_update(const f32x32& r, const f32x32& gv) {
    const f32x32 tt  = gv - r;
    const f32x32 qst = r + tt;
    return r - qst;
}

__device__ __forceinline__ short8 as_s8(uint4 u) {
    union { uint4 a; short8 b; } x; x.a = u; return x.b;
}
__device__ __forceinline__ unsigned pk_hi(float v0, float v1) {
    return (__float_as_uint(v0) >> 16) | (__float_as_uint(v1) & 0xFFFF0000u);
}
__device__ __forceinline__ float lo_rem(float v) {
    return v - __uint_as_float(__float_as_uint(v) & 0xFFFF0000u);
}
__device__ __forceinline__ unsigned umn(unsigned a, unsigned b) { return a < b ? a : b; }
__device__ __forceinline__ unsigned umx(unsigned a, unsigned b) { return a > b ? a : b; }

// ---------------------------------------------------------------------------
// Kernel P: codebook -> bf16 hi/lo MFMA fragments + exact norms (R14-proven).
__global__ __launch_bounds__(64) void rvq_prep(const float* __restrict__ cb,
                                               uint4* __restrict__ scb,
                                               float* __restrict__ normg) {
    const int cnd = blockIdx.x * 64 + threadIdx.x;       // 0..5119
    const f32x32 c = *(const f32x32*)(cb + (long)cnd * RVQ_D);
    normg[cnd] = tree_dot(c, c);
    const int q = cnd >> 9, cq = cnd & 511, ct = cq >> 4, col = cq & 15;
    const long base = (long)(q * 32 + ct) * 128 + col;
#pragma unroll
    for (int g = 0; g < 4; ++g)
#pragma unroll
        for (int sp = 0; sp < 2; ++sp) {
            unsigned u[4];
#pragma unroll
            for (int pr = 0; pr < 4; ++pr) {
                const int j = g * 8 + pr * 2;
                float v0 = c[j], v1 = c[j + 1];
                if (sp == 1) { v0 = lo_rem(v0); v1 = lo_rem(v1); }
                u[pr] = pk_hi(v0, v1);
            }
            scb[base + (g * 2 + sp) * 16] = make_uint4(u[0], u[1], u[2], u[3]);
        }
}

// ---------------------------------------------------------------------------
// Kernel S: search. ONE wave per block, 64 points, no __syncthreads.
// LDS union: ptfrag (E->hoist) shares 8 KB with m1key/m2h (publish->R).
__global__ __launch_bounds__(64, 2) void rvq_search(const float* __restrict__ z,
                                                    const float* __restrict__ cb,
                                                    const uint4* __restrict__ scb,
                                                    const float* __restrict__ normg,
                                                    float* __restrict__ iout) {
    __shared__ __align__(16) unsigned char smem[BPTS * 8 * 16];   // 8 KB union
    __shared__ float snorm_l[RVQ_C];              // 2 KB EXACT norms (no K!)
    __shared__ float rrbuf[BPTS];                 // 256 B

    uint4*          ptfrag  = (uint4*)smem;                          // 8 KB
    unsigned*       m1key_s = (unsigned*)smem;                       // 4.25 KB
    unsigned short* m2h_s   = (unsigned short*)(smem + BPTS * 17 * 4); // 2.1 KB

    const int t    = threadIdx.x;          // 0..63 == lane
    const int col  = t & 15;
    const int g    = t >> 4;
    const int sw0  = g ^ (col & 7);
    const int sw1  = (4 + g) ^ (col & 7);
    const long p   = (long)blockIdx.x * BPTS + t;

    f32x32 r = *(const f32x32*)(z + p * RVQ_D);

#pragma unroll 1
    for (int q = 0; q < RVQ_Q; ++q) {
        const float* cbq  = cb + (long)q * RVQ_C * RVQ_D;
        const uint4* scbq = scb + (long)q * 4096;

        // ---- norms -> LDS + ccm (wave max), rr + rrmax (wave max)
        float ccm = 0.0f;
#pragma unroll
        for (int n = 0; n < 8; ++n) {
            const float v = normg[q * RVQ_C + t + 64 * n];
            snorm_l[t + 64 * n] = v;
            ccm = fmaxf(ccm, v);
        }
#pragma unroll
        for (int m_ = 1; m_ <= 32; m_ <<= 1) ccm = fmaxf(ccm, __shfl_xor(ccm, m_, 64));

        const float rr = tree_dot(r, r);
        rrbuf[t] = rr;
        float rrmax = rr;
#pragma unroll
        for (int m_ = 1; m_ <= 32; m_ <<= 1) rrmax = fmaxf(rrmax, __shfl_xor(rrmax, m_, 64));
        const float biasW = (rrmax + ccm) * 0.001953125f;   // 2^-9 window
        const float K     = rrmax + biasW;   // uniform shift (R16/R17/R20-proven)

        // ---- E phase: -2r bf16 split -> ptfrag (proven bit-pattern)
        {
            const f32x32 s = -2.0f * r;
#pragma unroll
            for (int sp = 0; sp < 2; ++sp)
#pragma unroll
                for (int gg = 0; gg < 4; ++gg) {
                    unsigned u[4];
#pragma unroll
                    for (int pr = 0; pr < 4; ++pr) {
                        const int j = gg * 8 + pr * 2;
                        float v0 = s[j], v1 = s[j + 1];
                        if (sp == 1) { v0 = lo_rem(v0); v1 = lo_rem(v1); }
                        u[pr] = pk_hi(v0, v1);
                    }
                    ptfrag[t * 8 + ((sp * 4 + gg) ^ (t & 7))] =
                        make_uint4(u[0], u[1], u[2], u[3]);
                }
        }

        // ---- hoist A fragments (registers for whole sweep)
        uint4 ahr[4], alr[4];
#pragma unroll
        for (int TL = 0; TL < 4; ++TL) {
            ahr[TL] = ptfrag[(TL * 16 + col) * 8 + sw0];
            alr[TL] = ptfrag[(TL * 16 + col) * 8 + sw1];
        }

        // ---- packed-key trackers (registers, pure C ops)
        unsigned m1k[4][4], m2k[4][4];
#pragma unroll
        for (int a = 0; a < 4; ++a)
#pragma unroll
            for (int b = 0; b < 4; ++b) { m1k[a][b] = 0xFFFFFFFFu; m2k[a][b] = 0xFFFFFFFFu; }

        int cndv = col;   // candidate id of this lane's column

        // ---- sweep: candidate tile PAIRS, batch-2 merged tracker
#pragma unroll 2
        for (int ct = 0; ct < 32; ct += 2) {
            const short8 bhA = as_s8(scbq[ct * 128 + g * 32 + col]);
            const short8 blA = as_s8(scbq[ct * 128 + g * 32 + col + 16]);
            const short8 bhB = as_s8(scbq[(ct + 1) * 128 + g * 32 + col]);
            const short8 blB = as_s8(scbq[(ct + 1) * 128 + g * 32 + col + 16]);
            const float cKA = snorm_l[ct * 16 + col] + K;
            const float cKB = snorm_l[(ct + 1) * 16 + col] + K;
            const f32x4 accinA = {cKA, cKA, cKA, cKA};
            const f32x4 accinB = {cKB, cKB, cKB, cKB};
#pragma unroll
            for (int TL = 0; TL < 4; ++TL) {
                const short8 ah = as_s8(ahr[TL]);
                const short8 al = as_s8(alr[TL]);
                f32x4 accA = __builtin_amdgcn_mfma_f32_16x16x32_bf16(ah, bhA, accinA, 0, 0, 0);
                accA = __builtin_amdgcn_mfma_f32_16x16x32_bf16(al, bhA, accA, 0, 0, 0);
                accA = __builtin_amdgcn_mfma_f32_16x16x32_bf16(ah, blA, accA, 0, 0, 0);
                f32x4 accB = __builtin_amdgcn_mfma_f32_16x16x32_bf16(ah, bhB, accinB, 0, 0, 0);
                accB = __builtin_amdgcn_mfma_f32_16x16x32_bf16(al, bhB, accB, 0, 0, 0);
                accB = __builtin_amdgcn_mfma_f32_16x16x32_bf16(ah, blB, accB, 0, 0, 0);
#pragma unroll
                for (int i = 0; i < 4; ++i) {
                    const unsigned kA = (__float_as_uint(accA[i]) & KMASK) | (unsigned)cndv;
                    const unsigned kB = (__float_as_uint(accB[i]) & KMASK) | (unsigned)(cndv + 16);
                    // merged (m1,m2) <- two smallest of {m1,m2,kA,kB}:
                    // med-triple is LLVM's u32 med3 pattern -> v_med3_u32;
                    // m1 path folds to v_min3_u32.
                    const unsigned pmn = umn(kA, kB);
                    const unsigned med = umx(pmn, umn(umx(kA, kB), m1k[TL][i]));
                    m2k[TL][i] = umn(m2k[TL][i], med);
                    m1k[TL][i] = umn(m1k[TL][i], pmn);
                }
            }
            cndv += 32;
        }

        // ---- publish trackers (ptfrag dead; union reuse safe in wave order)
#pragma unroll
        for (int TL = 0; TL < 4; ++TL)
#pragma unroll
            for (int i = 0; i < 4; ++i) {
                const int pt = TL * 16 + 4 * g + i;
                m1key_s[pt * 17 + col] = m1k[TL][i];
                const float m2f = __uint_as_float(m2k[TL][i] & KMASK);
                m2h_s[pt * 17 + col] = __half_as_ushort(__float2half_rd(m2f));
            }

        // ---- R phase (R20-proven): admitted-id evals + coop scans
        float bd = __builtin_inff(); int bi = 0;
        unsigned smask = 0;
        {
            unsigned mmk = 0xFFFFFFFFu;
#pragma unroll
            for (int c = 0; c < 16; ++c) mmk = umn(mmk, m1key_s[t * 17 + c]);
            const float thrf = __uint_as_float(mmk & KMASK) + (rr + ccm) * 0.001953125f;

            auto evalExact = [&](int cnd) {
                const f32x32 cvv = *(const f32x32*)(cbq + (long)cnd * RVQ_D);
                const float d = fmaf(-2.0f, tree_dot(r, cvv), rr) + snorm_l[cnd];
                if (d < bd || (d == bd && cnd < bi)) { bd = d; bi = cnd; }
            };
#pragma unroll 1
            for (int c = 0; c < 16; ++c) {
                const unsigned k1 = m1key_s[t * 17 + c];
                const bool adm = __uint_as_float(k1 & KMASK) <= thrf;
                const bool scn = __half2float(__ushort_as_half(m2h_s[t * 17 + c])) <= thrf;
                smask |= (scn ? 1u : 0u) << c;
                if (adm && !scn) evalExact((int)(k1 & 511u));
            }

            // cooperative full-class scans (rare; R15-proven)
            unsigned long long bal = __ballot(smask != 0);
            const int l31 = t & 31;
            while (bal) {
                const int b = (int)__builtin_ctzll(bal); bal &= bal - 1;
                unsigned sm = (unsigned)__shfl((int)smask, b, 64);
                f32x32 rb;
#pragma unroll
                for (int j = 0; j < RVQ_D; ++j) rb[j] = __shfl(r[j], b, 64);
                const float rrb = __shfl(rr, b, 64);
                while (sm) {
                    const int c = (int)__builtin_ctz(sm); sm &= sm - 1;
                    int  ci = l31 * 16 + c;
                    const f32x32 cvv = *(const f32x32*)(cbq + (long)ci * RVQ_D);
                    float d = fmaf(-2.0f, tree_dot(rb, cvv), rrb) + snorm_l[ci];
#pragma unroll
                    for (int m_ = 1; m_ <= 32; m_ <<= 1) {
                        const float od = __shfl_xor(d, m_, 64);
                        const int   oi = __shfl_xor(ci, m_, 64);
                        if (od < d || (od == d && oi < ci)) { d = od; ci = oi; }
                    }
                    if (t == b) {
                        if (d < bd || (d == bd && ci < bi)) { bd = d; bi = ci; }
                    }
                }
            }
        }

        iout[p * RVQ_Q + q] = (float)bi;
        const f32x32 gw = *(const f32x32*)(cbq + (long)bi * RVQ_D);
        r = st_update(r, gw);
    }
}

// ---------------------------------------------------------------------------
// Replay: bit-exact straight-through chain from stored indices (proven
// pre+post-timing R3-R22). Overwrites the scratch region with quantized.
__global__ __launch_bounds__(256) void rvq_replay(const float* __restrict__ z,
                                                  const float* __restrict__ cb,
                                                  float* __restrict__ out) {
    const int p = blockIdx.x * 256 + threadIdx.x;

    float r[RVQ_D], oacc[RVQ_D];
    {
        const float4* zp = (const float4*)(z + (long)p * RVQ_D);
#pragma unroll
        for (int w = 0; w < 8; ++w) {
            const float4 v = zp[w];
            r[w * 4 + 0] = v.x; r[w * 4 + 1] = v.y;
            r[w * 4 + 2] = v.z; r[w * 4 + 3] = v.w;
        }
    }
#pragma unroll
    for (int d = 0; d < RVQ_D; ++d) oacc[d] = 0.0f;

#pragma unroll 1
    for (int q = 0; q < RVQ_Q; ++q) {
        const int idx = (int)out[IDX_OFF + (long)p * RVQ_Q + q];
        const float4* cwb = (const float4*)(cb + ((long)q * RVQ_C + idx) * RVQ_D);
        float cwv[RVQ_D];
#pragma unroll
        for (int w = 0; w < 8; ++w) {
            const float4 v = cwb[w];
            cwv[w * 4 + 0] = v.x; cwv[w * 4 + 1] = v.y;
            cwv[w * 4 + 2] = v.z; cwv[w * 4 + 3] = v.w;
        }
#pragma unroll
        for (int d = 0; d < RVQ_D; ++d) {
            const float qst = r[d] + (cwv[d] - r[d]);
            oacc[d] += qst;
            r[d] = r[d] - qst;
        }
    }

    float4* qo = (float4*)(out + (long)p * RVQ_D);
#pragma unroll
    for (int w = 0; w < 8; ++w) {
        float4 v;
        v.x = oacc[w * 4 + 0]; v.y = oacc[w * 4 + 1];
        v.z = oacc[w * 4 + 2]; v.w = oacc[w * 4 + 3];
        qo[w] = v;
    }

    if (p < RVQ_Q) out[LOSS_OFF + p] = 0.0f;
}

// ---------------------------------------------------------------------------
extern "C" void kernel_launch(void* const* d_in, const int* in_sizes, int n_in,
                              void* d_out, int out_size, void* d_ws, size_t ws_size,
                              hipStream_t stream) {
    const float* z  = (const float*)d_in[0];
    const float* cb = (const float*)d_in[1];
    float* out = (float*)d_out;
    (void)d_ws; (void)ws_size;   // no workspace (R6 lesson)

    // scratch inside the quantized region (rewritten every call; replay
    // overwrites it at the end — R4/R5/R14-R21-proven pattern)
    uint4* scb   = (uint4*)out;                 // 655 KB fragments
    float* normg = out + NORM_OFF;              // 5120 exact norms
    float* iout  = out + IDX_OFF;

    rvq_prep  <<<(RVQ_Q * RVQ_C) / 64, 64, 0, stream>>>(cb, scb, normg);
    rvq_search<<<NPTS / BPTS, BPTS, 0, stream>>>(z, cb, scb, normg, iout);
    rvq_replay<<<NPTS / 256, 256, 0, stream>>>(z, cb, out);
}